// Round 7
// baseline (225.930 us; speedup 1.0000x reference)
//
#include <hip/hip_runtime.h>
#include <math.h>
#include <stdint.h>

// TreeLSTM, 32 complete binary trees depth 10, heap order, d=128.
// R7: wx intermediate eliminated — level kernels compute W·x on the fly via
//     MFMA with duplicated-parent-row A operands (result lands in the exact
//     lane/reg the pair-sum epilogue needs). Child c staged coalesced into
//     LDS. Leaf kernel is leaves-only (no wx store). Tiled-transpose prep.
//     R6's hidden cost was per-lane scattered wx/c gathers in every level.

#define NTREES 32
#define MTREE 2047
#define NNODES (NTREES * MTREE)   // 65504

typedef __attribute__((ext_vector_type(8))) short bf16x8;
typedef __attribute__((ext_vector_type(4))) float f32x4;

__device__ __forceinline__ float sigmoidf_(float x) {
    return 1.0f / (1.0f + __expf(-x));
}
__device__ __forceinline__ float tanhf_(float x) {
    x = fminf(fmaxf(x, -10.0f), 10.0f);
    float e = __expf(2.0f * x);
    return (e - 1.0f) / (e + 1.0f);
}
__device__ __forceinline__ float bf2f(uint16_t b) {
    union { uint32_t u; float f; } v; v.u = ((uint32_t)b) << 16; return v.f;
}
__device__ __forceinline__ uint16_t f2bf(float f) {
    union { float f; uint32_t u; } v; v.f = f;
    uint32_t r = v.u + 0x7FFF + ((v.u >> 16) & 1);   // RNE
    return (uint16_t)(r >> 16);
}
__device__ __forceinline__ uint4 pack_bf8(float4 a, float4 b) {
    uint4 r;
    r.x = (uint32_t)f2bf(a.x) | ((uint32_t)f2bf(a.y) << 16);
    r.y = (uint32_t)f2bf(a.z) | ((uint32_t)f2bf(a.w) << 16);
    r.z = (uint32_t)f2bf(b.x) | ((uint32_t)f2bf(b.y) << 16);
    r.w = (uint32_t)f2bf(b.z) | ((uint32_t)f2bf(b.w) << 16);
    return r;
}

// Swizzled LDS layout: bf16 rows of 128 (16 chunks of 16B), XOR by row&7.
#define SWZ(row, chunk) ((row) * 128 + (((chunk) ^ ((row) & 7)) * 8))

// ---------------------------------------------------------------------------
// Prep: tiled transpose f32->bf16. Blocks 0..7 = 128x128 tiles, block 8 = bias.
__global__ __launch_bounds__(256) void prep_k(const float* __restrict__ Wiou,
                                              const float* __restrict__ Wf,
                                              const float* __restrict__ Uiou,
                                              const float* __restrict__ Uf,
                                              const float* __restrict__ biou,
                                              const float* __restrict__ bf,
                                              uint16_t* __restrict__ WT,
                                              uint16_t* __restrict__ UT,
                                              float* __restrict__ biasS) {
    const int b = blockIdx.x, tid = threadIdx.x;
    if (b == 8) {
#pragma unroll
        for (int r = 0; r < 2; ++r) {
            int j = r * 256 + tid;
            biasS[j] = j < 384 ? biou[j] : bf[j - 384];
        }
        return;
    }
    __shared__ float T[128 * 129];
    const float* src; int scols, n0; uint16_t* dst; int drow0;
    if (b < 3)       { src = Wiou; scols = 384; n0 = b * 128;       dst = WT; drow0 = b * 128; }
    else if (b == 3) { src = Wf;   scols = 128; n0 = 0;             dst = WT; drow0 = 384; }
    else if (b < 7)  { src = Uiou; scols = 384; n0 = (b - 4) * 128; dst = UT; drow0 = (b - 4) * 128; }
    else             { src = Uf;   scols = 128; n0 = 0;             dst = UT; drow0 = 384; }
#pragma unroll
    for (int i = 0; i < 16; ++i) {
        int idx4 = i * 256 + tid;          // 4096 quads
        int row = idx4 >> 5;
        int c4 = (idx4 & 31) * 4;
        float4 v = *(const float4*)&src[row * scols + n0 + c4];
        T[(c4 + 0) * 129 + row] = v.x;
        T[(c4 + 1) * 129 + row] = v.y;
        T[(c4 + 2) * 129 + row] = v.z;
        T[(c4 + 3) * 129 + row] = v.w;
    }
    __syncthreads();
#pragma unroll
    for (int i = 0; i < 16; ++i) {
        int idx4 = i * 256 + tid;
        int orow = idx4 >> 5;
        int k4 = (idx4 & 31) * 4;
        ushort4 o;
        o.x = f2bf(T[orow * 129 + k4 + 0]);
        o.y = f2bf(T[orow * 129 + k4 + 1]);
        o.z = f2bf(T[orow * 129 + k4 + 2]);
        o.w = f2bf(T[orow * 129 + k4 + 3]);
        *(ushort4*)&dst[(size_t)(drow0 + orow) * 128 + k4] = o;
    }
}

// ---------------------------------------------------------------------------
// Leaves only: h,c = lstm_leaf(W_iou^T x + b). 64 leaf rows/block (contiguous,
// always in-tree). Wave w owns col-tiles {w, w+8, w+16} = i/o/u of cols
// w*16..w*16+15 -> lane-local epilogue.
__global__ __launch_bounds__(512, 2) void leaf_k(const float* __restrict__ F,
                                                 const uint16_t* __restrict__ WT,
                                                 const float* __restrict__ biasS,
                                                 float* __restrict__ h,
                                                 float* __restrict__ c) {
    __shared__ uint16_t Fs[64 * 128];
    const int tid = threadIdx.x;
    const int w = tid >> 6, lane = tid & 63, q = lane >> 4, l15 = lane & 15;
    const int tree = blockIdx.x >> 4, grp = blockIdx.x & 15;
    const int v0 = tree * MTREE + 1023 + grp * 64;

#pragma unroll
    for (int r = 0; r < 2; ++r) {
        int ci = r * 512 + tid;
        int row = ci >> 4, cx = ci & 15;
        const float* src = F + (size_t)(v0 + row) * 128 + cx * 8;
        float4 f0 = *(const float4*)src;
        float4 f1 = *(const float4*)(src + 4);
        *(uint4*)&Fs[SWZ(row, cx)] = pack_bf8(f0, f1);
    }
    bf16x8 aW[3][4];
    float4 bias4[3];
#pragma unroll
    for (int s = 0; s < 3; ++s) {
        int row = (w + s * 8) * 16 + l15;
#pragma unroll
        for (int kc = 0; kc < 4; ++kc)
            aW[s][kc] = *(const bf16x8*)(WT + (size_t)row * 128 + kc * 32 + q * 8);
        bias4[s] = *(const float4*)(biasS + (w + s * 8) * 16 + q * 4);
    }
    __syncthreads();

#pragma unroll
    for (int nt = 0; nt < 4; ++nt) {
        bf16x8 b[4];
#pragma unroll
        for (int kc = 0; kc < 4; ++kc)
            b[kc] = *(const bf16x8*)&Fs[SWZ(nt * 16 + l15, kc * 4 + q)];
        f32x4 acc[3] = {};
#pragma unroll
        for (int s = 0; s < 3; ++s)
#pragma unroll
            for (int kc = 0; kc < 4; ++kc)
                acc[s] = __builtin_amdgcn_mfma_f32_16x16x32_bf16(aW[s][kc], b[kc], acc[s], 0, 0, 0);

        int v = v0 + nt * 16 + l15;
        int colb = w * 16 + q * 4;
        float cv[4], hv[4];
#pragma unroll
        for (int r = 0; r < 4; ++r) {
            float iv = sigmoidf_(acc[0][r] + bias4[0][r]);
            float ov = sigmoidf_(acc[1][r] + bias4[1][r]);
            float uv = tanhf_(acc[2][r] + bias4[2][r]);
            float cn = iv * uv;
            cv[r] = cn;
            hv[r] = ov * tanhf_(cn);
        }
        *(float4*)&c[(size_t)v * 128 + colb] = *(float4*)cv;
        *(float4*)&h[(size_t)v * 128 + colb] = *(float4*)hv;
    }
}

// ---------------------------------------------------------------------------
__device__ __forceinline__ void load_bUW(const uint16_t* __restrict__ UT,
                                         const uint16_t* __restrict__ WT,
                                         bf16x8 bU[4][4], bf16x8 bW[4][4]) {
    const int tid = threadIdx.x;
    const int w = tid >> 6, lane = tid & 63, q = lane >> 4, l15 = lane & 15;
#pragma unroll
    for (int s = 0; s < 4; ++s) {
        int row = (w + s * 8) * 16 + l15;   // s: 0=i,1=o,2=u,3=f col blocks
#pragma unroll
        for (int kc = 0; kc < 4; ++kc) {
            bU[s][kc] = *(const bf16x8*)(UT + (size_t)row * 128 + kc * 32 + q * 8);
            bW[s][kc] = *(const bf16x8*)(WT + (size_t)row * 128 + kc * 32 + q * 8);
        }
    }
}

// ---------------------------------------------------------------------------
// Big levels (dep 9/8/7): 32 parents/block. Child h + parent features staged
// bf16; child c staged f32 (stride 132). U·h per child, W·x per parent via
// duplicated-A-row MFMA; lane-local pair-sum epilogue; one barrier.
__global__ __launch_bounds__(512, 2) void big_level_k(const float* __restrict__ F,
                                                      const uint16_t* __restrict__ WT,
                                                      const uint16_t* __restrict__ UT,
                                                      const float* __restrict__ biasS,
                                                      float* __restrict__ h,
                                                      float* __restrict__ c,
                                                      int dep) {
    __shared__ uint16_t Hc[64 * 128];     // 16 KB child h
    __shared__ uint16_t FeatB[32 * 128];  // 8 KB parent x
    __shared__ float CSB[64 * 132];       // 33.8 KB child c
    const int tid = threadIdx.x;
    const int w = tid >> 6, lane = tid & 63, q = lane >> 4, l15 = lane & 15;
    const int colf = w * 16 + l15;
    bf16x8 bU[4][4], bW[4][4];
    load_bUW(UT, WT, bU, bW);
    const float bias_i = biasS[colf], bias_o = biasS[128 + colf];
    const float bias_u = biasS[256 + colf], bias_f = biasS[384 + colf];

    const int idx0 = blockIdx.x * 32;
    const int tree = idx0 >> dep;
    const int pos0 = idx0 - (tree << dep);
    const int np = 1 << dep;
    const int vp = tree * MTREE + (np - 1) + pos0;
    const int vc = tree * MTREE + (2 * np - 1) + 2 * pos0;

    // stage child h (1024 chunks) + parent features (512 chunks)
#pragma unroll
    for (int t = 0; t < 3; ++t) {
        int ci = t * 512 + tid;
        if (ci < 1024) {
            int row = ci >> 4, cx = ci & 15;
            const float* src = h + (size_t)(vc + row) * 128 + cx * 8;
            float4 f0 = *(const float4*)src;
            float4 f1 = *(const float4*)(src + 4);
            *(uint4*)&Hc[SWZ(row, cx)] = pack_bf8(f0, f1);
        } else {
            int ci2 = ci - 1024;
            int row = ci2 >> 4, cx = ci2 & 15;
            const float* src = F + (size_t)(vp + row) * 128 + cx * 8;
            float4 f0 = *(const float4*)src;
            float4 f1 = *(const float4*)(src + 4);
            *(uint4*)&FeatB[SWZ(row, cx)] = pack_bf8(f0, f1);
        }
    }
    // stage child c (2048 quads, coalesced)
#pragma unroll
    for (int t = 0; t < 4; ++t) {
        int ci = t * 512 + tid;
        int row = ci >> 5, c4 = (ci & 31) * 4;
        *(float4*)&CSB[row * 132 + c4] = *(const float4*)&c[(size_t)(vc + row) * 128 + c4];
    }
    __syncthreads();

#pragma unroll
    for (int ct = 0; ct < 4; ++ct) {
        bf16x8 a[4], ad[4];
#pragma unroll
        for (int kc = 0; kc < 4; ++kc) {
            a[kc]  = *(const bf16x8*)&Hc[SWZ(ct * 16 + l15, kc * 4 + q)];
            ad[kc] = *(const bf16x8*)&FeatB[SWZ(ct * 8 + (l15 >> 1), kc * 4 + q)];
        }
        f32x4 accU[4] = {}, accW[4] = {};
#pragma unroll
        for (int s = 0; s < 4; ++s)
#pragma unroll
            for (int kc = 0; kc < 4; ++kc) {
                accU[s] = __builtin_amdgcn_mfma_f32_16x16x32_bf16(a[kc],  bU[s][kc], accU[s], 0, 0, 0);
                accW[s] = __builtin_amdgcn_mfma_f32_16x16x32_bf16(ad[kc], bW[s][kc], accW[s], 0, 0, 0);
            }
        float fc[4];
#pragma unroll
        for (int r = 0; r < 4; ++r) {
            float cch = CSB[(ct * 16 + q * 4 + r) * 132 + colf];
            fc[r] = sigmoidf_(accU[3][r] + accW[3][r] + bias_f) * cch;
        }
#pragma unroll
        for (int j = 0; j < 2; ++j) {
            int pl = ct * 8 + q * 2 + j;
            float ip = accU[0][2 * j] + accU[0][2 * j + 1] + accW[0][2 * j] + bias_i;
            float op = accU[1][2 * j] + accU[1][2 * j + 1] + accW[1][2 * j] + bias_o;
            float up = accU[2][2 * j] + accU[2][2 * j + 1] + accW[2][2 * j] + bias_u;
            float cn = sigmoidf_(ip) * tanhf_(up) + fc[2 * j] + fc[2 * j + 1];
            float hv = sigmoidf_(op) * tanhf_(cn);
            c[(size_t)(vp + pl) * 128 + colf] = cn;
            h[(size_t)(vp + pl) * 128 + colf] = hv;
        }
    }
}

// ---------------------------------------------------------------------------
// Tail: dep 6..0, one block per tree. h in LDS (alternating halves), c in LDS
// CS halves, parent features staged once (tree-local rows 0..126). One barrier
// per group. W·x via duplicated-A-row MFMA from Feat LDS.
__global__ __launch_bounds__(512, 1) void tail_k(const float* __restrict__ F,
                                                 const uint16_t* __restrict__ WT,
                                                 const uint16_t* __restrict__ UT,
                                                 const float* __restrict__ biasS,
                                                 const float* __restrict__ cglob,
                                                 float* __restrict__ h) {
    __shared__ uint16_t Hbuf[192 * 128];   // 48 KB
    __shared__ float CS[128 * 132];        // 66 KB
    __shared__ uint16_t Feat[128 * 128];   // 32 KB (rows 0..126 used)
    const int tid = threadIdx.x;
    const int w = tid >> 6, lane = tid & 63, q = lane >> 4, l15 = lane & 15;
    const int colf = w * 16 + l15;
    const int tree = blockIdx.x;
    const int vbase = tree * MTREE;
    bf16x8 bU[4][4], bW[4][4];
    load_bUW(UT, WT, bU, bW);
    const float bias_i = biasS[colf], bias_o = biasS[128 + colf];
    const float bias_u = biasS[256 + colf], bias_f = biasS[384 + colf];

    // stage dep-7 h (tree-local 127..254) -> Hbuf rows 0..127
#pragma unroll
    for (int t = 0; t < 4; ++t) {
        int ci = t * 512 + tid;
        int row = ci >> 4, cx = ci & 15;
        const float* src = h + (size_t)(vbase + 127 + row) * 128 + cx * 8;
        float4 f0 = *(const float4*)src;
        float4 f1 = *(const float4*)(src + 4);
        *(uint4*)&Hbuf[SWZ(row, cx)] = pack_bf8(f0, f1);
    }
    // stage parent features (tree-local 0..126) -> Feat rows 0..126
#pragma unroll
    for (int t = 0; t < 4; ++t) {
        int ci = t * 512 + tid;
        if (ci < 2032) {
            int row = ci >> 4, cx = ci & 15;
            const float* src = F + (size_t)(vbase + row) * 128 + cx * 8;
            float4 f0 = *(const float4*)src;
            float4 f1 = *(const float4*)(src + 4);
            *(uint4*)&Feat[SWZ(row, cx)] = pack_bf8(f0, f1);
        }
    }

#pragma unroll 1
    for (int gi = 0; gi < 8; ++gi) {
        const int dep = gi < 2 ? 6 : 7 - gi;
        const int np = 1 << dep;
        const int pos0 = (gi == 1) ? 32 : 0;
        const int P = gi < 3 ? 32 : np;
        const int pL = dep & 1;
        const int childBase = pL ? 128 : 0;
        const int parBase = pL ? 0 : 128;
        const int csRead = pL ? 0 : 64;
        const int csWrite = pL ? 64 : 0;
        const int vp = vbase + (np - 1) + pos0;
        const int pfeat0 = (np - 1) + pos0;
        __syncthreads();

#pragma unroll
        for (int ct = 0; ct < 4; ++ct) {
            bf16x8 a[4], ad[4];
#pragma unroll
            for (int kc = 0; kc < 4; ++kc) {
                a[kc]  = *(const bf16x8*)&Hbuf[SWZ(childBase + 2 * pos0 + ct * 16 + l15, kc * 4 + q)];
                ad[kc] = *(const bf16x8*)&Feat[SWZ(pfeat0 + ct * 8 + (l15 >> 1), kc * 4 + q)];
            }
            f32x4 accU[4] = {}, accW[4] = {};
#pragma unroll
            for (int s = 0; s < 4; ++s)
#pragma unroll
                for (int kc = 0; kc < 4; ++kc) {
                    accU[s] = __builtin_amdgcn_mfma_f32_16x16x32_bf16(a[kc],  bU[s][kc], accU[s], 0, 0, 0);
                    accW[s] = __builtin_amdgcn_mfma_f32_16x16x32_bf16(ad[kc], bW[s][kc], accW[s], 0, 0, 0);
                }
            float fc[4];
#pragma unroll
            for (int r = 0; r < 4; ++r) {
                float cch;
                if (gi < 2) {
                    int cl = 2 * pos0 + ct * 16 + q * 4 + r;
                    cch = cglob[(size_t)(vbase + 127 + cl) * 128 + colf];
                } else {
                    int cl = ct * 16 + q * 4 + r;
                    cch = CS[(csRead + cl) * 132 + colf];
                }
                fc[r] = sigmoidf_(accU[3][r] + accW[3][r] + bias_f) * cch;
            }
#pragma unroll
            for (int j = 0; j < 2; ++j) {
                int pl = ct * 8 + q * 2 + j;
                float ip = accU[0][2 * j] + accU[0][2 * j + 1] + accW[0][2 * j] + bias_i;
                float op = accU[1][2 * j] + accU[1][2 * j + 1] + accW[1][2 * j] + bias_o;
                float up = accU[2][2 * j] + accU[2][2 * j + 1] + accW[2][2 * j] + bias_u;
                float cn = sigmoidf_(ip) * tanhf_(up) + fc[2 * j] + fc[2 * j + 1];
                float hv = sigmoidf_(op) * tanhf_(cn);
                if (pl < P) {
                    h[(size_t)(vp + pl) * 128 + colf] = hv;
                    int row = parBase + pos0 + pl;
                    Hbuf[row * 128 + (((colf >> 3) ^ (row & 7)) * 8) + (colf & 7)] = f2bf(hv);
                    CS[(csWrite + pos0 + pl) * 132 + colf] = cn;
                }
            }
        }
    }
}

// ---------------------------------------------------------------------------
extern "C" void kernel_launch(void* const* d_in, const int* in_sizes, int n_in,
                              void* d_out, int out_size, void* d_ws, size_t ws_size,
                              hipStream_t stream) {
    const float* features = (const float*)d_in[0];
    const float* W_iou    = (const float*)d_in[1];
    const float* b_iou    = (const float*)d_in[2];
    const float* U_iou    = (const float*)d_in[3];
    const float* W_f      = (const float*)d_in[4];
    const float* b_f      = (const float*)d_in[5];
    const float* U_f      = (const float*)d_in[6];
    float* h = (float*)d_out;

    // ws: c f32 [NNODES][128] | WT | UT | biasS  (~34 MB)
    char* wp = (char*)d_ws;
    float*    c     = (float*)wp;    wp += (size_t)NNODES * 128 * 4;
    uint16_t* WT    = (uint16_t*)wp; wp += 512 * 128 * 2;
    uint16_t* UT    = (uint16_t*)wp; wp += 512 * 128 * 2;
    float*    biasS = (float*)wp;    wp += 512 * 4;

    hipLaunchKernelGGL(prep_k, dim3(9), dim3(256), 0, stream,
                       W_iou, W_f, U_iou, U_f, b_iou, b_f, WT, UT, biasS);
    hipLaunchKernelGGL(leaf_k, dim3(512), dim3(512), 0, stream,
                       features, WT, biasS, h, c);
    hipLaunchKernelGGL(big_level_k, dim3(512), dim3(512), 0, stream,
                       features, WT, UT, biasS, h, c, 9);
    hipLaunchKernelGGL(big_level_k, dim3(256), dim3(512), 0, stream,
                       features, WT, UT, biasS, h, c, 8);
    hipLaunchKernelGGL(big_level_k, dim3(128), dim3(512), 0, stream,
                       features, WT, UT, biasS, h, c, 7);
    hipLaunchKernelGGL(tail_k, dim3(32), dim3(512), 0, stream,
                       features, WT, UT, biasS, c, h);
}